// Round 2
// baseline (1606.309 us; speedup 1.0000x reference)
//
#include <hip/hip_runtime.h>
#include <hip/hip_bf16.h>
#include <math.h>

#define N_NODES 40000
#define NE      640000
#define FIN     33
#define H       128
#define COUT    3
#define NLAYERS 8
#define ALPHA   0.1f
#define THETA   0.5f
#define SCAN_B  157            // ceil(N_NODES / 256)

// ---------------- CSR build ----------------
__global__ void k_hist(const int* __restrict__ row, int* __restrict__ counts) {
    int e = blockIdx.x * blockDim.x + threadIdx.x;
    if (e < NE) atomicAdd(&counts[row[e]], 1);
}

// phase 1: per-block inclusive scan of 256 counts; write exclusive (no base), block total
__global__ __launch_bounds__(256) void k_scan1(const int* __restrict__ counts,
                        int* __restrict__ row_ptr, int* __restrict__ partial) {
    __shared__ int s[256];
    int t = threadIdx.x, i = blockIdx.x * 256 + t;
    int v = (i < N_NODES) ? counts[i] : 0;
    s[t] = v;
    __syncthreads();
    for (int off = 1; off < 256; off <<= 1) {
        int x = s[t];
        int add = (t >= off) ? s[t - off] : 0;
        __syncthreads();
        s[t] = x + add;
        __syncthreads();
    }
    if (i < N_NODES) row_ptr[i] = s[t] - v;      // exclusive within block
    if (t == 255) partial[blockIdx.x] = s[255];
}

// phase 2: single block scans the 157 block totals -> exclusive bases (in place)
__global__ __launch_bounds__(256) void k_scan2(int* __restrict__ partial) {
    __shared__ int s[256];
    int t = threadIdx.x;
    int v = (t < SCAN_B) ? partial[t] : 0;
    s[t] = v;
    __syncthreads();
    for (int off = 1; off < 256; off <<= 1) {
        int x = s[t];
        int add = (t >= off) ? s[t - off] : 0;
        __syncthreads();
        s[t] = x + add;
        __syncthreads();
    }
    if (t < SCAN_B) partial[t] = s[t] - v;       // exclusive base
}

// phase 3: add base, init cursor, close row_ptr
__global__ __launch_bounds__(256) void k_scan3(const int* __restrict__ partial,
                        int* __restrict__ row_ptr, int* __restrict__ cursor) {
    int t = threadIdx.x, i = blockIdx.x * 256 + t;
    if (i < N_NODES) {
        int v = row_ptr[i] + partial[blockIdx.x];
        row_ptr[i] = v;
        cursor[i] = v;
    }
    if (i == 0) row_ptr[N_NODES] = NE;
}

__global__ void k_scatter(const int* __restrict__ row, const int* __restrict__ col,
                          const float* __restrict__ w, int* __restrict__ cursor,
                          int* __restrict__ scol, float* __restrict__ sw) {
    int e = blockIdx.x * blockDim.x + threadIdx.x;
    if (e < NE) {
        int r = row[e];
        int pos = atomicAdd(&cursor[r], 1);
        scol[pos] = col[e];
        sw[pos] = (1.0f - ALPHA) * w[e];   // fold (1-alpha) into edge weight
    }
}

// ---------------- x0 = relu(x @ W_in^T + b_in); h = x0 ----------------
// 16 nodes per block -> 2500 blocks; W_in staged once per block
__global__ __launch_bounds__(256) void k_xin(const float* __restrict__ x,
                      const float* __restrict__ Win, const float* __restrict__ bin,
                      float* __restrict__ x0, float* __restrict__ h) {
    __shared__ float sW[H * FIN];      // 16.9 KB
    __shared__ float sx[16][FIN];      // 2.1 KB
    int t = threadIdx.x;
    for (int i = t; i < H * FIN; i += 256) sW[i] = Win[i];
    int n0 = blockIdx.x * 16;
    for (int i = t; i < 16 * FIN; i += 256)
        sx[i / FIN][i % FIN] = x[(size_t)(n0 + i / FIN) * FIN + (i % FIN)];
    __syncthreads();
    int f = t % H;
    int l0 = t / H;                    // 0..1
    float bv = bin[f];
    for (int lo = l0; lo < 16; lo += 2) {
        float acc = bv;
        #pragma unroll
        for (int k = 0; k < FIN; k++) acc += sx[lo][k] * sW[f * FIN + k];
        acc = fmaxf(acc, 0.f);
        int n = n0 + lo;
        x0[(size_t)n * H + f] = acc;
        h [(size_t)n * H + f] = acc;
    }
}

// ---------------- fused layer: h_out = h_in + relu((1-b)*xx + b*(xx@W)) ----
// xx = A@h_in (weights pre-scaled by 1-alpha) + alpha*x0, built in LDS.
// block: 256 threads, 32 rows; thread = 4 rows x 4 cols in the GEMM.
__global__ __launch_bounds__(256) void k_layer(const int* __restrict__ row_ptr,
                       const int* __restrict__ scol, const float* __restrict__ sw,
                       const float* __restrict__ h_in, const float* __restrict__ x0,
                       const float* __restrict__ W, float* __restrict__ h_out,
                       float beta) {
    __shared__ float sX[32][H + 1];    // 16.5 KB xx tile
    __shared__ float sW[64][H];        // 32 KB K-chunk of W
    int t = threadIdx.x;
    int row0 = blockIdx.x * 32;
    int wv = t >> 6, lane = t & 63;

    // gather phase: wave wv builds rows row0+wv*8 .. +7
    for (int rr = 0; rr < 8; rr++) {
        int r = row0 + wv * 8 + rr;
        int beg = row_ptr[r], end = row_ptr[r + 1];
        float2 acc = {0.f, 0.f};
        for (int e = beg; e < end; e++) {
            int c = scol[e];
            float w = sw[e];
            float2 v = ((const float2*)(h_in + (size_t)c * H))[lane];
            acc.x += w * v.x; acc.y += w * v.y;
        }
        float2 xv = ((const float2*)(x0 + (size_t)r * H))[lane];
        sX[wv * 8 + rr][lane * 2]     = acc.x + ALPHA * xv.x;
        sX[wv * 8 + rr][lane * 2 + 1] = acc.y + ALPHA * xv.y;
    }

    // GEMM phase
    int tx = t % 32;
    int ty = t / 32;                   // 0..7
    float acc[4][4] = {};
    for (int kk = 0; kk < H; kk += 64) {
        __syncthreads();               // first pass also guards gather->sX
        for (int i = t; i < 64 * H; i += 256)
            sW[i / H][i % H] = W[(size_t)(kk + i / H) * H + (i % H)];
        __syncthreads();
        for (int k = 0; k < 64; k++) {
            float b0 = sW[k][tx], b1 = sW[k][tx + 32], b2 = sW[k][tx + 64], b3 = sW[k][tx + 96];
            #pragma unroll
            for (int r = 0; r < 4; r++) {
                float a = sX[ty * 4 + r][kk + k];
                acc[r][0] += a * b0; acc[r][1] += a * b1;
                acc[r][2] += a * b2; acc[r][3] += a * b3;
            }
        }
    }
    float omb = 1.f - beta;
    #pragma unroll
    for (int r = 0; r < 4; r++) {
        int n = row0 + ty * 4 + r;
        #pragma unroll
        for (int c = 0; c < 4; c++) {
            int col = tx + 32 * c;
            float xv = sX[ty * 4 + r][col];
            float o = omb * xv + beta * acc[r][c];
            h_out[(size_t)n * H + col] = h_in[(size_t)n * H + col] + fmaxf(o, 0.f);
        }
    }
}

// ---------------- out = h @ W_out^T + b_out  (wave per node) ----------------
__global__ __launch_bounds__(256) void k_out(const float* __restrict__ h,
                      const float* __restrict__ Wout, const float* __restrict__ bout,
                      float* __restrict__ out) {
    int wave = (blockIdx.x * blockDim.x + threadIdx.x) >> 6;
    int lane = threadIdx.x & 63;
    if (wave >= N_NODES) return;
    float2 v = ((const float2*)(h + (size_t)wave * H))[lane];
    float p0, p1, p2;
    {
        float2 w0 = ((const float2*)(Wout + 0 * H))[lane];
        float2 w1 = ((const float2*)(Wout + 1 * H))[lane];
        float2 w2 = ((const float2*)(Wout + 2 * H))[lane];
        p0 = v.x * w0.x + v.y * w0.y;
        p1 = v.x * w1.x + v.y * w1.y;
        p2 = v.x * w2.x + v.y * w2.y;
    }
    #pragma unroll
    for (int off = 32; off > 0; off >>= 1) {
        p0 += __shfl_down(p0, off);
        p1 += __shfl_down(p1, off);
        p2 += __shfl_down(p2, off);
    }
    if (lane == 0) {
        out[(size_t)wave * 3 + 0] = p0 + bout[0];
        out[(size_t)wave * 3 + 1] = p1 + bout[1];
        out[(size_t)wave * 3 + 2] = p2 + bout[2];
    }
}

extern "C" void kernel_launch(void* const* d_in, const int* in_sizes, int n_in,
                              void* d_out, int out_size, void* d_ws, size_t ws_size,
                              hipStream_t stream) {
    const float* x     = (const float*)d_in[0];
    const int*   erow  = (const int*)  d_in[1];
    const int*   ecol  = (const int*)  d_in[2];
    const float* ew    = (const float*)d_in[3];
    const float* Win   = (const float*)d_in[4];
    const float* bin   = (const float*)d_in[5];
    const float* Wout  = (const float*)d_in[6];
    const float* bout  = (const float*)d_in[7];
    const float* Wconv = (const float*)d_in[8];
    float* out = (float*)d_out;

    char* ws = (char*)d_ws;
    const size_t NH = (size_t)N_NODES * H * sizeof(float);   // 20,480,000 B
    float* x0      = (float*)(ws);
    float* hA      = (float*)(ws + NH);
    float* hB      = (float*)(ws + 2 * NH);
    char*  p       = ws + 3 * NH;
    int*   counts  = (int*)  p;  p += 160256;   // N ints, padded
    int*   row_ptr = (int*)  p;  p += 160256;   // N+1 ints, padded
    int*   cursor  = (int*)  p;  p += 160256;   // N ints, padded
    int*   partial = (int*)  p;  p += 1024;     // 157 ints, padded
    int*   scol    = (int*)  p;  p += (size_t)NE * 4;
    float* sw      = (float*)p;

    // CSR build (every call; ws re-poisoned each launch)
    hipMemsetAsync(counts, 0, (size_t)N_NODES * 4, stream);
    k_hist   <<<NE / 256, 256, 0, stream>>>(erow, counts);
    k_scan1  <<<SCAN_B,   256, 0, stream>>>(counts, row_ptr, partial);
    k_scan2  <<<1,        256, 0, stream>>>(partial);
    k_scan3  <<<SCAN_B,   256, 0, stream>>>(partial, row_ptr, cursor);
    k_scatter<<<NE / 256, 256, 0, stream>>>(erow, ecol, ew, cursor, scol, sw);

    // input projection (writes x0 and hA)
    k_xin<<<N_NODES / 16, 256, 0, stream>>>(x, Win, bin, x0, hA);

    // fused layers with h ping-pong (8 layers: ends back in hA)
    for (int l = 0; l < NLAYERS; l++) {
        float beta = logf(THETA / (float)(l + 1) + 1.0f);
        const float* hin = (l & 1) ? hB : hA;
        float*       hout = (l & 1) ? hA : hB;
        k_layer<<<N_NODES / 32, 256, 0, stream>>>(row_ptr, scol, sw, hin, x0,
                                                  Wconv + (size_t)l * H * H, hout, beta);
    }

    // output projection (final h is in hA after 8 layers)
    k_out<<<N_NODES / 4, 256, 0, stream>>>(hA, Wout, bout, out);
}

// Round 3
// 796.165 us; speedup vs baseline: 2.0176x; 2.0176x over previous
//
#include <hip/hip_runtime.h>
#include <hip/hip_bf16.h>
#include <math.h>

#define N_NODES 40000
#define NE      640000
#define FIN     33
#define H       128
#define COUT    3
#define NLAYERS 8
#define ALPHA   0.1f
#define THETA   0.5f
#define SCAN_B  157            // ceil(N_NODES / 256)

// ---------------- CSR build ----------------
__global__ void k_hist(const int* __restrict__ row, int* __restrict__ counts) {
    int e = blockIdx.x * blockDim.x + threadIdx.x;
    if (e < NE) atomicAdd(&counts[row[e]], 1);
}

__global__ __launch_bounds__(256) void k_scan1(const int* __restrict__ counts,
                        int* __restrict__ row_ptr, int* __restrict__ partial) {
    __shared__ int s[256];
    int t = threadIdx.x, i = blockIdx.x * 256 + t;
    int v = (i < N_NODES) ? counts[i] : 0;
    s[t] = v;
    __syncthreads();
    for (int off = 1; off < 256; off <<= 1) {
        int x = s[t];
        int add = (t >= off) ? s[t - off] : 0;
        __syncthreads();
        s[t] = x + add;
        __syncthreads();
    }
    if (i < N_NODES) row_ptr[i] = s[t] - v;      // exclusive within block
    if (t == 255) partial[blockIdx.x] = s[255];
}

__global__ __launch_bounds__(256) void k_scan2(int* __restrict__ partial) {
    __shared__ int s[256];
    int t = threadIdx.x;
    int v = (t < SCAN_B) ? partial[t] : 0;
    s[t] = v;
    __syncthreads();
    for (int off = 1; off < 256; off <<= 1) {
        int x = s[t];
        int add = (t >= off) ? s[t - off] : 0;
        __syncthreads();
        s[t] = x + add;
        __syncthreads();
    }
    if (t < SCAN_B) partial[t] = s[t] - v;       // exclusive base
}

__global__ __launch_bounds__(256) void k_scan3(const int* __restrict__ partial,
                        int* __restrict__ row_ptr, int* __restrict__ cursor) {
    int t = threadIdx.x, i = blockIdx.x * 256 + t;
    if (i < N_NODES) {
        int v = row_ptr[i] + partial[blockIdx.x];
        row_ptr[i] = v;
        cursor[i] = v;
    }
    if (i == 0) row_ptr[N_NODES] = NE;
}

// pack (col, w*(1-alpha)) into int2 -> one 8B load per edge in spmm
__global__ void k_scatter(const int* __restrict__ row, const int* __restrict__ col,
                          const float* __restrict__ w, int* __restrict__ cursor,
                          int2* __restrict__ ep) {
    int e = blockIdx.x * blockDim.x + threadIdx.x;
    if (e < NE) {
        int r = row[e];
        int pos = atomicAdd(&cursor[r], 1);
        ep[pos] = make_int2(col[e], __float_as_int((1.0f - ALPHA) * w[e]));
    }
}

// ---- x0 = relu(x @ W_in^T + b_in); hA = x0 (fp32); x0bf, hbf = bf16(x0) ----
__global__ __launch_bounds__(256) void k_xin(const float* __restrict__ x,
                      const float* __restrict__ Win, const float* __restrict__ bin,
                      float* __restrict__ h, __hip_bfloat16* __restrict__ x0bf,
                      __hip_bfloat16* __restrict__ hbf) {
    __shared__ float sW[H * FIN];      // 16.9 KB
    __shared__ float sx[16][FIN];      // 2.1 KB
    int t = threadIdx.x;
    for (int i = t; i < H * FIN; i += 256) sW[i] = Win[i];
    int n0 = blockIdx.x * 16;
    for (int i = t; i < 16 * FIN; i += 256)
        sx[i / FIN][i % FIN] = x[(size_t)(n0 + i / FIN) * FIN + (i % FIN)];
    __syncthreads();
    int f = t % H;
    int l0 = t / H;                    // 0..1
    float bv = bin[f];
    for (int lo = l0; lo < 16; lo += 2) {
        float acc = bv;
        #pragma unroll
        for (int k = 0; k < FIN; k++) acc += sx[lo][k] * sW[f * FIN + k];
        acc = fmaxf(acc, 0.f);
        size_t idx = (size_t)(n0 + lo) * H + f;
        h[idx] = acc;
        __hip_bfloat16 b = __float2bfloat16(acc);
        x0bf[idx] = b;
        hbf[idx] = b;
    }
}

// ---- xx = A@hbf (w pre-scaled by 1-alpha) + alpha*x0bf, accumulate fp32 ----
// wave per row; bf16 gather halves L2/L3 traffic (256 B/row)
__global__ __launch_bounds__(256) void k_spmm(const int* __restrict__ row_ptr,
                       const int2* __restrict__ ep,
                       const __hip_bfloat16* __restrict__ hbf,
                       const __hip_bfloat16* __restrict__ x0bf,
                       float* __restrict__ xx) {
    int wave = (blockIdx.x * blockDim.x + threadIdx.x) >> 6;
    int lane = threadIdx.x & 63;
    if (wave >= N_NODES) return;
    int beg = row_ptr[wave], end = row_ptr[wave + 1];
    float ax = 0.f, ay = 0.f, bx = 0.f, by = 0.f;   // 2 independent chains (ILP)
    int e = beg;
    for (; e + 2 <= end; e += 2) {
        int2 p0 = ep[e], p1 = ep[e + 1];
        float w0 = __int_as_float(p0.y), w1 = __int_as_float(p1.y);
        __hip_bfloat162 v0 = ((const __hip_bfloat162*)(hbf + (size_t)p0.x * H))[lane];
        __hip_bfloat162 v1 = ((const __hip_bfloat162*)(hbf + (size_t)p1.x * H))[lane];
        ax += w0 * __bfloat162float(v0.x); ay += w0 * __bfloat162float(v0.y);
        bx += w1 * __bfloat162float(v1.x); by += w1 * __bfloat162float(v1.y);
    }
    if (e < end) {
        int2 p = ep[e];
        float w = __int_as_float(p.y);
        __hip_bfloat162 v = ((const __hip_bfloat162*)(hbf + (size_t)p.x * H))[lane];
        ax += w * __bfloat162float(v.x); ay += w * __bfloat162float(v.y);
    }
    __hip_bfloat162 xv = ((const __hip_bfloat162*)(x0bf + (size_t)wave * H))[lane];
    float2 o;
    o.x = ax + bx + ALPHA * __bfloat162float(xv.x);
    o.y = ay + by + ALPHA * __bfloat162float(xv.y);
    ((float2*)(xx + (size_t)wave * H))[lane] = o;
}

// ---- h_out = h_in + relu((1-b)*xx + b*(xx@W)); hbf = bf16(h_out) ----------
// IN-PLACE: hx holds xx on entry, h_out on exit (each block reads its own
// 32-row tile into LDS before overwriting it; no cross-block overlap).
__global__ __launch_bounds__(256) void k_gemm(float* hx,
                       const float* __restrict__ h_in, const float* __restrict__ W,
                       __hip_bfloat16* __restrict__ hbf, float beta) {
    __shared__ float sW[64][H];        // 32 KB (K-chunk of W)
    __shared__ float sX[32][H + 1];    // 16.5 KB, padded
    int t = threadIdx.x;
    int row0 = blockIdx.x * 32;
    for (int i = t; i < 32 * H; i += 256) {
        int r = i / H, k = i % H;
        sX[r][k] = hx[(size_t)(row0 + r) * H + k];
    }
    int tx = t % 32;
    int ty = t / 32;                   // 0..7
    float acc[4][4] = {};
    for (int kk = 0; kk < H; kk += 64) {
        __syncthreads();               // first pass also guards sX staging
        for (int i = t; i < 64 * H; i += 256)
            sW[i / H][i % H] = W[(size_t)(kk + i / H) * H + (i % H)];
        __syncthreads();
        for (int k = 0; k < 64; k++) {
            float b0 = sW[k][tx], b1 = sW[k][tx + 32], b2 = sW[k][tx + 64], b3 = sW[k][tx + 96];
            #pragma unroll
            for (int r = 0; r < 4; r++) {
                float a = sX[ty * 4 + r][kk + k];
                acc[r][0] += a * b0; acc[r][1] += a * b1;
                acc[r][2] += a * b2; acc[r][3] += a * b3;
            }
        }
    }
    float omb = 1.f - beta;
    #pragma unroll
    for (int r = 0; r < 4; r++) {
        int n = row0 + ty * 4 + r;
        #pragma unroll
        for (int c = 0; c < 4; c++) {
            int col = tx + 32 * c;
            float xv = sX[ty * 4 + r][col];
            size_t idx = (size_t)n * H + col;
            float o = h_in[idx] + fmaxf(omb * xv + beta * acc[r][c], 0.f);
            hx[idx] = o;
            hbf[idx] = __float2bfloat16(o);
        }
    }
}

// ---------------- out = h @ W_out^T + b_out  (wave per node) ----------------
__global__ __launch_bounds__(256) void k_out(const float* __restrict__ h,
                      const float* __restrict__ Wout, const float* __restrict__ bout,
                      float* __restrict__ out) {
    int wave = (blockIdx.x * blockDim.x + threadIdx.x) >> 6;
    int lane = threadIdx.x & 63;
    if (wave >= N_NODES) return;
    float2 v = ((const float2*)(h + (size_t)wave * H))[lane];
    float p0, p1, p2;
    {
        float2 w0 = ((const float2*)(Wout + 0 * H))[lane];
        float2 w1 = ((const float2*)(Wout + 1 * H))[lane];
        float2 w2 = ((const float2*)(Wout + 2 * H))[lane];
        p0 = v.x * w0.x + v.y * w0.y;
        p1 = v.x * w1.x + v.y * w1.y;
        p2 = v.x * w2.x + v.y * w2.y;
    }
    #pragma unroll
    for (int off = 32; off > 0; off >>= 1) {
        p0 += __shfl_down(p0, off);
        p1 += __shfl_down(p1, off);
        p2 += __shfl_down(p2, off);
    }
    if (lane == 0) {
        out[(size_t)wave * 3 + 0] = p0 + bout[0];
        out[(size_t)wave * 3 + 1] = p1 + bout[1];
        out[(size_t)wave * 3 + 2] = p2 + bout[2];
    }
}

extern "C" void kernel_launch(void* const* d_in, const int* in_sizes, int n_in,
                              void* d_out, int out_size, void* d_ws, size_t ws_size,
                              hipStream_t stream) {
    const float* x     = (const float*)d_in[0];
    const int*   erow  = (const int*)  d_in[1];
    const int*   ecol  = (const int*)  d_in[2];
    const float* ew    = (const float*)d_in[3];
    const float* Win   = (const float*)d_in[4];
    const float* bin   = (const float*)d_in[5];
    const float* Wout  = (const float*)d_in[6];
    const float* bout  = (const float*)d_in[7];
    const float* Wconv = (const float*)d_in[8];
    float* out = (float*)d_out;

    // workspace layout: 67,041,792 B total (same envelope as verified rounds)
    char* ws = (char*)d_ws;
    const size_t NHf = (size_t)N_NODES * H * sizeof(float);          // 20,480,000
    const size_t NHb = (size_t)N_NODES * H * sizeof(__hip_bfloat16); // 10,240,000
    float*          hA    = (float*)(ws);
    float*          hB    = (float*)(ws + NHf);
    __hip_bfloat16* x0bf  = (__hip_bfloat16*)(ws + 2 * NHf);
    __hip_bfloat16* hbf   = (__hip_bfloat16*)(ws + 2 * NHf + NHb);
    char* p = ws + 2 * NHf + 2 * NHb;
    int*  counts  = (int*) p;  p += 160256;
    int*  row_ptr = (int*) p;  p += 160256;
    int*  cursor  = (int*) p;  p += 160256;
    int*  partial = (int*) p;  p += 1024;
    int2* ep      = (int2*)p;                  // NE * 8 bytes

    // CSR build (inputs restored pristine before every call)
    hipMemsetAsync(counts, 0, (size_t)N_NODES * 4, stream);
    k_hist   <<<NE / 256, 256, 0, stream>>>(erow, counts);
    k_scan1  <<<SCAN_B,   256, 0, stream>>>(counts, row_ptr, partial);
    k_scan2  <<<1,        256, 0, stream>>>(partial);
    k_scan3  <<<SCAN_B,   256, 0, stream>>>(partial, row_ptr, cursor);
    k_scatter<<<NE / 256, 256, 0, stream>>>(erow, ecol, ew, cursor, ep);

    // input projection
    k_xin<<<N_NODES / 16, 256, 0, stream>>>(x, Win, bin, hA, x0bf, hbf);

    // layers: spmm writes xx into the h_out buffer; gemm finishes in place
    for (int l = 0; l < NLAYERS; l++) {
        float beta = logf(THETA / (float)(l + 1) + 1.0f);
        const float* hin  = (l & 1) ? hB : hA;
        float*       hout = (l & 1) ? hA : hB;
        k_spmm<<<N_NODES / 4, 256, 0, stream>>>(row_ptr, ep, hbf, x0bf, hout);
        k_gemm<<<N_NODES / 32, 256, 0, stream>>>(hout, hin,
                                                 Wconv + (size_t)l * H * H, hbf, beta);
    }

    // output projection (8 layers -> final h in hA)
    k_out<<<N_NODES / 4, 256, 0, stream>>>(hA, Wout, bout, out);
}

// Round 4
// 665.470 us; speedup vs baseline: 2.4138x; 1.1964x over previous
//
#include <hip/hip_runtime.h>
#include <hip/hip_bf16.h>
#include <math.h>

#define N_NODES 40000
#define NE      640000
#define FIN     33
#define H       128
#define COUT    3
#define NLAYERS 8
#define ALPHA   0.1f
#define THETA   0.5f
#define SCAN_B  157            // ceil(N_NODES / 256)

typedef __bf16 bf16x8 __attribute__((ext_vector_type(8)));
typedef float  f32x4  __attribute__((ext_vector_type(4)));

__device__ inline unsigned short f2bf(float f) {
    __hip_bfloat16 b = __float2bfloat16(f);
    return *(unsigned short*)&b;
}

// ---------------- CSR build ----------------
__global__ void k_hist(const int* __restrict__ row, int* __restrict__ counts) {
    int e = blockIdx.x * blockDim.x + threadIdx.x;
    if (e < NE) atomicAdd(&counts[row[e]], 1);
}

__global__ __launch_bounds__(256) void k_scan1(const int* __restrict__ counts,
                        int* __restrict__ row_ptr, int* __restrict__ partial) {
    __shared__ int s[256];
    int t = threadIdx.x, i = blockIdx.x * 256 + t;
    int v = (i < N_NODES) ? counts[i] : 0;
    s[t] = v;
    __syncthreads();
    for (int off = 1; off < 256; off <<= 1) {
        int x = s[t];
        int add = (t >= off) ? s[t - off] : 0;
        __syncthreads();
        s[t] = x + add;
        __syncthreads();
    }
    if (i < N_NODES) row_ptr[i] = s[t] - v;      // exclusive within block
    if (t == 255) partial[blockIdx.x] = s[255];
}

__global__ __launch_bounds__(256) void k_scan2(int* __restrict__ partial) {
    __shared__ int s[256];
    int t = threadIdx.x;
    int v = (t < SCAN_B) ? partial[t] : 0;
    s[t] = v;
    __syncthreads();
    for (int off = 1; off < 256; off <<= 1) {
        int x = s[t];
        int add = (t >= off) ? s[t - off] : 0;
        __syncthreads();
        s[t] = x + add;
        __syncthreads();
    }
    if (t < SCAN_B) partial[t] = s[t] - v;       // exclusive base
}

__global__ __launch_bounds__(256) void k_scan3(const int* __restrict__ partial,
                        int* __restrict__ row_ptr, int* __restrict__ cursor) {
    int t = threadIdx.x, i = blockIdx.x * 256 + t;
    if (i < N_NODES) {
        int v = row_ptr[i] + partial[blockIdx.x];
        row_ptr[i] = v;
        cursor[i] = v;
    }
    if (i == 0) row_ptr[N_NODES] = NE;
}

__global__ void k_scatter(const int* __restrict__ row, const int* __restrict__ col,
                          const float* __restrict__ w, int* __restrict__ cursor,
                          int2* __restrict__ ep) {
    int e = blockIdx.x * blockDim.x + threadIdx.x;
    if (e < NE) {
        int r = row[e];
        int pos = atomicAdd(&cursor[r], 1);
        ep[pos] = make_int2(col[e], __float_as_int((1.0f - ALPHA) * w[e]));
    }
}

// ---- Wtbf[l][j][k] = bf16(W[l][k][j])  (B operand for MFMA, row = output col)
__global__ __launch_bounds__(256) void k_wprep(const float* __restrict__ W,
                        unsigned short* __restrict__ Wtbf) {
    int idx = blockIdx.x * 256 + threadIdx.x;     // 8*128*128 = 131072
    int l = idx >> 14;
    int rem = idx & 16383;
    int k = rem >> 7, j = rem & 127;
    Wtbf[l * 16384 + j * 128 + k] = f2bf(W[idx]); // W[idx] = W[l][k][j], coalesced read
}

// ---- x0 = relu(x @ W_in^T + b_in); h = x0 (fp32); x0bf, hbf = bf16(x0) ----
__global__ __launch_bounds__(256) void k_xin(const float* __restrict__ x,
                      const float* __restrict__ Win, const float* __restrict__ bin,
                      float* __restrict__ h, unsigned short* __restrict__ x0bf,
                      unsigned short* __restrict__ hbf) {
    __shared__ float sW[H * FIN];      // 16.9 KB
    __shared__ float sx[16][FIN];      // 2.1 KB
    int t = threadIdx.x;
    for (int i = t; i < H * FIN; i += 256) sW[i] = Win[i];
    int n0 = blockIdx.x * 16;
    for (int i = t; i < 16 * FIN; i += 256)
        sx[i / FIN][i % FIN] = x[(size_t)(n0 + i / FIN) * FIN + (i % FIN)];
    __syncthreads();
    int f = t % H;
    int l0 = t / H;                    // 0..1
    float bv = bin[f];
    for (int lo = l0; lo < 16; lo += 2) {
        float acc = bv;
        #pragma unroll
        for (int k = 0; k < FIN; k++) acc += sx[lo][k] * sW[f * FIN + k];
        acc = fmaxf(acc, 0.f);
        size_t idx = (size_t)(n0 + lo) * H + f;
        h[idx] = acc;
        unsigned short b = f2bf(acc);
        x0bf[idx] = b;
        hbf[idx] = b;
    }
}

// ---- xx = A@hbf (w pre-scaled by 1-alpha) + alpha*x0bf, fp32 accumulate ----
// wave per row; bf16 gather (256 B/row); 4 independent chains for MLP
__global__ __launch_bounds__(256) void k_spmm(const int* __restrict__ row_ptr,
                       const int2* __restrict__ ep,
                       const unsigned short* __restrict__ hbf,
                       const unsigned short* __restrict__ x0bf,
                       float* __restrict__ xx) {
    int wave = (blockIdx.x * blockDim.x + threadIdx.x) >> 6;
    int lane = threadIdx.x & 63;
    if (wave >= N_NODES) return;
    int beg = row_ptr[wave], end = row_ptr[wave + 1];
    float ax0 = 0.f, ay0 = 0.f, ax1 = 0.f, ay1 = 0.f;
    float ax2 = 0.f, ay2 = 0.f, ax3 = 0.f, ay3 = 0.f;
    int e = beg;
    for (; e + 4 <= end; e += 4) {
        int2 p0 = ep[e], p1 = ep[e + 1], p2 = ep[e + 2], p3 = ep[e + 3];
        float w0 = __int_as_float(p0.y), w1 = __int_as_float(p1.y);
        float w2 = __int_as_float(p2.y), w3 = __int_as_float(p3.y);
        __hip_bfloat162 v0 = ((const __hip_bfloat162*)(hbf + (size_t)p0.x * H))[lane];
        __hip_bfloat162 v1 = ((const __hip_bfloat162*)(hbf + (size_t)p1.x * H))[lane];
        __hip_bfloat162 v2 = ((const __hip_bfloat162*)(hbf + (size_t)p2.x * H))[lane];
        __hip_bfloat162 v3 = ((const __hip_bfloat162*)(hbf + (size_t)p3.x * H))[lane];
        ax0 += w0 * __bfloat162float(v0.x); ay0 += w0 * __bfloat162float(v0.y);
        ax1 += w1 * __bfloat162float(v1.x); ay1 += w1 * __bfloat162float(v1.y);
        ax2 += w2 * __bfloat162float(v2.x); ay2 += w2 * __bfloat162float(v2.y);
        ax3 += w3 * __bfloat162float(v3.x); ay3 += w3 * __bfloat162float(v3.y);
    }
    for (; e < end; e++) {
        int2 p = ep[e];
        float w = __int_as_float(p.y);
        __hip_bfloat162 v = ((const __hip_bfloat162*)(hbf + (size_t)p.x * H))[lane];
        ax0 += w * __bfloat162float(v.x); ay0 += w * __bfloat162float(v.y);
    }
    __hip_bfloat162 xv = ((const __hip_bfloat162*)(x0bf + (size_t)wave * H))[lane];
    float2 o;
    o.x = (ax0 + ax1) + (ax2 + ax3) + ALPHA * __bfloat162float(xv.x);
    o.y = (ay0 + ay1) + (ay2 + ay3) + ALPHA * __bfloat162float(xv.y);
    ((float2*)(xx + (size_t)wave * H))[lane] = o;
}

// ---- MFMA GEMM + epilogue: h += relu((1-b)*xx + b*(xx@W)); hbf = bf16(h) --
// block = 4 waves, 64 rows; wave = 16 rows x 128 cols (8 16x16 acc tiles).
// A = bf16(xx) converted in-reg; B = Wtbf (global, L1-hot, no LDS).
__global__ __launch_bounds__(256) void k_gemm(float* __restrict__ xx,
                       float* __restrict__ h, const unsigned short* __restrict__ Wtbf,
                       unsigned short* __restrict__ hbf, float beta) {
    int t = threadIdx.x;
    int wv = t >> 6, lane = t & 63;
    int quad = lane >> 4, l16 = lane & 15;
    int rbase = blockIdx.x * 64 + wv * 16;

    f32x4 acc[8];
    #pragma unroll
    for (int j = 0; j < 8; j++) acc[j] = (f32x4){0.f, 0.f, 0.f, 0.f};

    #pragma unroll
    for (int k0 = 0; k0 < 4; k0++) {
        // A fragment: xx[rbase+l16][k0*32 + quad*8 .. +7] -> bf16x8
        const float* ap = xx + (size_t)(rbase + l16) * H + k0 * 32 + quad * 8;
        union { unsigned short u[8]; bf16x8 v; } af;
        #pragma unroll
        for (int i = 0; i < 8; i++) af.u[i] = f2bf(ap[i]);
        #pragma unroll
        for (int j = 0; j < 8; j++) {
            // B fragment: Wt[j*16+l16][k0*32 + quad*8 .. +7]
            bf16x8 bf = *(const bf16x8*)(Wtbf + (size_t)(j * 16 + l16) * H + k0 * 32 + quad * 8);
            acc[j] = __builtin_amdgcn_mfma_f32_16x16x32_bf16(af.v, bf, acc[j], 0, 0, 0);
        }
    }

    float omb = 1.f - beta;
    #pragma unroll
    for (int j = 0; j < 8; j++) {
        #pragma unroll
        for (int r = 0; r < 4; r++) {
            int row = rbase + quad * 4 + r;        // C/D: row = quad*4 + reg
            int col = j * 16 + l16;                //      col = lane & 15
            size_t idx = (size_t)row * H + col;
            float sk = xx[idx];                    // fp32 skip term
            float o = omb * sk + beta * acc[j][r];
            float hv = h[idx] + fmaxf(o, 0.f);
            h[idx] = hv;
            hbf[idx] = f2bf(hv);
        }
    }
}

// ---------------- out = h @ W_out^T + b_out  (wave per node) ----------------
__global__ __launch_bounds__(256) void k_out(const float* __restrict__ h,
                      const float* __restrict__ Wout, const float* __restrict__ bout,
                      float* __restrict__ out) {
    int wave = (blockIdx.x * blockDim.x + threadIdx.x) >> 6;
    int lane = threadIdx.x & 63;
    if (wave >= N_NODES) return;
    float2 v = ((const float2*)(h + (size_t)wave * H))[lane];
    float p0, p1, p2;
    {
        float2 w0 = ((const float2*)(Wout + 0 * H))[lane];
        float2 w1 = ((const float2*)(Wout + 1 * H))[lane];
        float2 w2 = ((const float2*)(Wout + 2 * H))[lane];
        p0 = v.x * w0.x + v.y * w0.y;
        p1 = v.x * w1.x + v.y * w1.y;
        p2 = v.x * w2.x + v.y * w2.y;
    }
    #pragma unroll
    for (int off = 32; off > 0; off >>= 1) {
        p0 += __shfl_down(p0, off);
        p1 += __shfl_down(p1, off);
        p2 += __shfl_down(p2, off);
    }
    if (lane == 0) {
        out[(size_t)wave * 3 + 0] = p0 + bout[0];
        out[(size_t)wave * 3 + 1] = p1 + bout[1];
        out[(size_t)wave * 3 + 2] = p2 + bout[2];
    }
}

extern "C" void kernel_launch(void* const* d_in, const int* in_sizes, int n_in,
                              void* d_out, int out_size, void* d_ws, size_t ws_size,
                              hipStream_t stream) {
    const float* x     = (const float*)d_in[0];
    const int*   erow  = (const int*)  d_in[1];
    const int*   ecol  = (const int*)  d_in[2];
    const float* ew    = (const float*)d_in[3];
    const float* Win   = (const float*)d_in[4];
    const float* bin   = (const float*)d_in[5];
    const float* Wout  = (const float*)d_in[6];
    const float* bout  = (const float*)d_in[7];
    const float* Wconv = (const float*)d_in[8];
    float* out = (float*)d_out;

    char* ws = (char*)d_ws;
    const size_t NHf = (size_t)N_NODES * H * sizeof(float);           // 20,480,000
    const size_t NHb = (size_t)N_NODES * H * sizeof(unsigned short);  // 10,240,000
    float*          h     = (float*)(ws);
    float*          xx    = (float*)(ws + NHf);
    unsigned short* x0bf  = (unsigned short*)(ws + 2 * NHf);
    unsigned short* hbf   = (unsigned short*)(ws + 2 * NHf + NHb);
    char* p = ws + 2 * NHf + 2 * NHb;
    unsigned short* Wtbf  = (unsigned short*)p;  p += 8 * H * H * 2;  // 262,144
    int*  counts  = (int*) p;  p += 160256;
    int*  row_ptr = (int*) p;  p += 160256;
    int*  cursor  = (int*) p;  p += 160256;
    int*  partial = (int*) p;  p += 1024;
    int2* ep      = (int2*)p;                    // NE * 8 bytes

    // CSR build (inputs restored pristine before every call)
    hipMemsetAsync(counts, 0, (size_t)N_NODES * 4, stream);
    k_hist   <<<NE / 256, 256, 0, stream>>>(erow, counts);
    k_scan1  <<<SCAN_B,   256, 0, stream>>>(counts, row_ptr, partial);
    k_scan2  <<<1,        256, 0, stream>>>(partial);
    k_scan3  <<<SCAN_B,   256, 0, stream>>>(partial, row_ptr, cursor);
    k_scatter<<<NE / 256, 256, 0, stream>>>(erow, ecol, ew, cursor, ep);

    // weight prep + input projection
    k_wprep<<<8 * H * H / 256, 256, 0, stream>>>(Wconv, Wtbf);
    k_xin  <<<N_NODES / 16,    256, 0, stream>>>(x, Win, bin, h, x0bf, hbf);

    // layers: spmm -> xx (fp32); gemm: h += relu(...), refresh hbf
    for (int l = 0; l < NLAYERS; l++) {
        float beta = logf(THETA / (float)(l + 1) + 1.0f);
        k_spmm<<<N_NODES / 4,  256, 0, stream>>>(row_ptr, ep, hbf, x0bf, xx);
        k_gemm<<<N_NODES / 64, 256, 0, stream>>>(xx, h, Wtbf + (size_t)l * H * H, hbf, beta);
    }

    // output projection
    k_out<<<N_NODES / 4, 256, 0, stream>>>(h, Wout, bout, out);
}

// Round 5
// 650.165 us; speedup vs baseline: 2.4706x; 1.0235x over previous
//
#include <hip/hip_runtime.h>
#include <hip/hip_bf16.h>
#include <math.h>

#define N_NODES 40000
#define NE      640000
#define FIN     33
#define H       128
#define COUT    3
#define NLAYERS 8
#define ALPHA   0.1f
#define THETA   0.5f
#define SCAN_B  157            // ceil(N_NODES / 256)

typedef __bf16 bf16x8 __attribute__((ext_vector_type(8)));
typedef float  f32x4  __attribute__((ext_vector_type(4)));

__device__ inline unsigned short f2bf(float f) {
    __hip_bfloat16 b = __float2bfloat16(f);
    return *(unsigned short*)&b;
}
__device__ inline float bf2f(unsigned short u) {
    __hip_bfloat16 b = *(__hip_bfloat16*)&u;
    return __bfloat162float(b);
}

// ---------------- CSR build ----------------
__global__ void k_hist(const int* __restrict__ row, int* __restrict__ counts) {
    int e = blockIdx.x * blockDim.x + threadIdx.x;
    if (e < NE) atomicAdd(&counts[row[e]], 1);
}

__global__ __launch_bounds__(256) void k_scan1(const int* __restrict__ counts,
                        int* __restrict__ row_ptr, int* __restrict__ partial) {
    __shared__ int s[256];
    int t = threadIdx.x, i = blockIdx.x * 256 + t;
    int v = (i < N_NODES) ? counts[i] : 0;
    s[t] = v;
    __syncthreads();
    for (int off = 1; off < 256; off <<= 1) {
        int x = s[t];
        int add = (t >= off) ? s[t - off] : 0;
        __syncthreads();
        s[t] = x + add;
        __syncthreads();
    }
    if (i < N_NODES) row_ptr[i] = s[t] - v;      // exclusive within block
    if (t == 255) partial[blockIdx.x] = s[255];
}

__global__ __launch_bounds__(256) void k_scan2(int* __restrict__ partial) {
    __shared__ int s[256];
    int t = threadIdx.x;
    int v = (t < SCAN_B) ? partial[t] : 0;
    s[t] = v;
    __syncthreads();
    for (int off = 1; off < 256; off <<= 1) {
        int x = s[t];
        int add = (t >= off) ? s[t - off] : 0;
        __syncthreads();
        s[t] = x + add;
        __syncthreads();
    }
    if (t < SCAN_B) partial[t] = s[t] - v;       // exclusive base
}

__global__ __launch_bounds__(256) void k_scan3(const int* __restrict__ partial,
                        int* __restrict__ row_ptr, int* __restrict__ cursor) {
    int t = threadIdx.x, i = blockIdx.x * 256 + t;
    if (i < N_NODES) {
        int v = row_ptr[i] + partial[blockIdx.x];
        row_ptr[i] = v;
        cursor[i] = v;
    }
    if (i == 0) row_ptr[N_NODES] = NE;
}

__global__ void k_scatter(const int* __restrict__ row, const int* __restrict__ col,
                          const float* __restrict__ w, int* __restrict__ cursor,
                          int2* __restrict__ ep) {
    int e = blockIdx.x * blockDim.x + threadIdx.x;
    if (e < NE) {
        int r = row[e];
        int pos = atomicAdd(&cursor[r], 1);
        ep[pos] = make_int2(col[e], __float_as_int((1.0f - ALPHA) * w[e]));
    }
}

// ---- Wtbf[l][j][k] = bf16(W[l][k][j])  (B operand for MFMA, row = output col)
__global__ __launch_bounds__(256) void k_wprep(const float* __restrict__ W,
                        unsigned short* __restrict__ Wtbf) {
    int idx = blockIdx.x * 256 + threadIdx.x;     // 8*128*128 = 131072
    int l = idx >> 14;
    int rem = idx & 16383;
    int k = rem >> 7, j = rem & 127;
    Wtbf[l * 16384 + j * 128 + k] = f2bf(W[idx]); // W[idx] = W[l][k][j], coalesced read
}

// ---- x0 = relu(x @ W_in^T + b_in); h = x0 (fp32); x0bf, hbf = bf16(x0) ----
__global__ __launch_bounds__(256) void k_xin(const float* __restrict__ x,
                      const float* __restrict__ Win, const float* __restrict__ bin,
                      float* __restrict__ h, unsigned short* __restrict__ x0bf,
                      unsigned short* __restrict__ hbf) {
    __shared__ float sW[H * FIN];      // 16.9 KB
    __shared__ float sx[16][FIN];      // 2.1 KB
    int t = threadIdx.x;
    for (int i = t; i < H * FIN; i += 256) sW[i] = Win[i];
    int n0 = blockIdx.x * 16;
    for (int i = t; i < 16 * FIN; i += 256)
        sx[i / FIN][i % FIN] = x[(size_t)(n0 + i / FIN) * FIN + (i % FIN)];
    __syncthreads();
    int f = t % H;
    int l0 = t / H;                    // 0..1
    float bv = bin[f];
    for (int lo = l0; lo < 16; lo += 2) {
        float acc = bv;
        #pragma unroll
        for (int k = 0; k < FIN; k++) acc += sx[lo][k] * sW[f * FIN + k];
        acc = fmaxf(acc, 0.f);
        size_t idx = (size_t)(n0 + lo) * H + f;
        h[idx] = acc;
        unsigned short b = f2bf(acc);
        x0bf[idx] = b;
        hbf[idx] = b;
    }
}

// ---- xx = A@hbf (w pre-scaled by 1-alpha) + alpha*x0bf -> bf16 out --------
// wave per row; bf16 gather (256 B/row); 4 independent chains for MLP
__global__ __launch_bounds__(256) void k_spmm(const int* __restrict__ row_ptr,
                       const int2* __restrict__ ep,
                       const unsigned short* __restrict__ hbf,
                       const unsigned short* __restrict__ x0bf,
                       unsigned short* __restrict__ xxbf) {
    int wave = (blockIdx.x * blockDim.x + threadIdx.x) >> 6;
    int lane = threadIdx.x & 63;
    if (wave >= N_NODES) return;
    int beg = row_ptr[wave], end = row_ptr[wave + 1];
    float ax0 = 0.f, ay0 = 0.f, ax1 = 0.f, ay1 = 0.f;
    float ax2 = 0.f, ay2 = 0.f, ax3 = 0.f, ay3 = 0.f;
    int e = beg;
    for (; e + 4 <= end; e += 4) {
        int2 p0 = ep[e], p1 = ep[e + 1], p2 = ep[e + 2], p3 = ep[e + 3];
        float w0 = __int_as_float(p0.y), w1 = __int_as_float(p1.y);
        float w2 = __int_as_float(p2.y), w3 = __int_as_float(p3.y);
        __hip_bfloat162 v0 = ((const __hip_bfloat162*)(hbf + (size_t)p0.x * H))[lane];
        __hip_bfloat162 v1 = ((const __hip_bfloat162*)(hbf + (size_t)p1.x * H))[lane];
        __hip_bfloat162 v2 = ((const __hip_bfloat162*)(hbf + (size_t)p2.x * H))[lane];
        __hip_bfloat162 v3 = ((const __hip_bfloat162*)(hbf + (size_t)p3.x * H))[lane];
        ax0 += w0 * __bfloat162float(v0.x); ay0 += w0 * __bfloat162float(v0.y);
        ax1 += w1 * __bfloat162float(v1.x); ay1 += w1 * __bfloat162float(v1.y);
        ax2 += w2 * __bfloat162float(v2.x); ay2 += w2 * __bfloat162float(v2.y);
        ax3 += w3 * __bfloat162float(v3.x); ay3 += w3 * __bfloat162float(v3.y);
    }
    for (; e < end; e++) {
        int2 p = ep[e];
        float w = __int_as_float(p.y);
        __hip_bfloat162 v = ((const __hip_bfloat162*)(hbf + (size_t)p.x * H))[lane];
        ax0 += w * __bfloat162float(v.x); ay0 += w * __bfloat162float(v.y);
    }
    __hip_bfloat162 xv = ((const __hip_bfloat162*)(x0bf + (size_t)wave * H))[lane];
    float ox = (ax0 + ax1) + (ax2 + ax3) + ALPHA * __bfloat162float(xv.x);
    float oy = (ay0 + ay1) + (ay2 + ay3) + ALPHA * __bfloat162float(xv.y);
    ushort2 o = make_ushort2(f2bf(ox), f2bf(oy));
    ((ushort2*)(xxbf + (size_t)wave * H))[lane] = o;
}

// ---- MFMA GEMM + epilogue: h += relu((1-b)*xx + b*(xx@W)); hbf = bf16(h) --
// block = 4 waves, 64 rows; wave = 16 rows x 128 cols (8 16x16 acc tiles).
// A = xxbf loaded directly (bf16, no cvt); B = Wtbf (global, L1-hot, no LDS).
__global__ __launch_bounds__(256) void k_gemm(const unsigned short* __restrict__ xxbf,
                       float* __restrict__ h, const unsigned short* __restrict__ Wtbf,
                       unsigned short* __restrict__ hbf, float beta) {
    int t = threadIdx.x;
    int wv = t >> 6, lane = t & 63;
    int quad = lane >> 4, l16 = lane & 15;
    int rbase = blockIdx.x * 64 + wv * 16;

    f32x4 acc[8];
    #pragma unroll
    for (int j = 0; j < 8; j++) acc[j] = (f32x4){0.f, 0.f, 0.f, 0.f};

    #pragma unroll
    for (int k0 = 0; k0 < 4; k0++) {
        // A fragment: xxbf[rbase+l16][k0*32 + quad*8 .. +7]
        bf16x8 av = *(const bf16x8*)(xxbf + (size_t)(rbase + l16) * H + k0 * 32 + quad * 8);
        #pragma unroll
        for (int j = 0; j < 8; j++) {
            // B fragment: Wt[j*16+l16][k0*32 + quad*8 .. +7]
            bf16x8 bv = *(const bf16x8*)(Wtbf + (size_t)(j * 16 + l16) * H + k0 * 32 + quad * 8);
            acc[j] = __builtin_amdgcn_mfma_f32_16x16x32_bf16(av, bv, acc[j], 0, 0, 0);
        }
    }

    float omb = 1.f - beta;
    #pragma unroll
    for (int j = 0; j < 8; j++) {
        #pragma unroll
        for (int r = 0; r < 4; r++) {
            int row = rbase + quad * 4 + r;        // C/D: row = quad*4 + reg
            int col = j * 16 + l16;                //      col = lane & 15
            size_t idx = (size_t)row * H + col;
            float sk = bf2f(xxbf[idx]);            // skip term (bf16)
            float o = omb * sk + beta * acc[j][r];
            float hv = h[idx] + fmaxf(o, 0.f);
            h[idx] = hv;
            hbf[idx] = f2bf(hv);
        }
    }
}

// ---------------- out = h @ W_out^T + b_out  (wave per node) ----------------
__global__ __launch_bounds__(256) void k_out(const float* __restrict__ h,
                      const float* __restrict__ Wout, const float* __restrict__ bout,
                      float* __restrict__ out) {
    int wave = (blockIdx.x * blockDim.x + threadIdx.x) >> 6;
    int lane = threadIdx.x & 63;
    if (wave >= N_NODES) return;
    float2 v = ((const float2*)(h + (size_t)wave * H))[lane];
    float p0, p1, p2;
    {
        float2 w0 = ((const float2*)(Wout + 0 * H))[lane];
        float2 w1 = ((const float2*)(Wout + 1 * H))[lane];
        float2 w2 = ((const float2*)(Wout + 2 * H))[lane];
        p0 = v.x * w0.x + v.y * w0.y;
        p1 = v.x * w1.x + v.y * w1.y;
        p2 = v.x * w2.x + v.y * w2.y;
    }
    #pragma unroll
    for (int off = 32; off > 0; off >>= 1) {
        p0 += __shfl_down(p0, off);
        p1 += __shfl_down(p1, off);
        p2 += __shfl_down(p2, off);
    }
    if (lane == 0) {
        out[(size_t)wave * 3 + 0] = p0 + bout[0];
        out[(size_t)wave * 3 + 1] = p1 + bout[1];
        out[(size_t)wave * 3 + 2] = p2 + bout[2];
    }
}

extern "C" void kernel_launch(void* const* d_in, const int* in_sizes, int n_in,
                              void* d_out, int out_size, void* d_ws, size_t ws_size,
                              hipStream_t stream) {
    const float* x     = (const float*)d_in[0];
    const int*   erow  = (const int*)  d_in[1];
    const int*   ecol  = (const int*)  d_in[2];
    const float* ew    = (const float*)d_in[3];
    const float* Win   = (const float*)d_in[4];
    const float* bin   = (const float*)d_in[5];
    const float* Wout  = (const float*)d_in[6];
    const float* bout  = (const float*)d_in[7];
    const float* Wconv = (const float*)d_in[8];
    float* out = (float*)d_out;

    char* ws = (char*)d_ws;
    const size_t NHf = (size_t)N_NODES * H * sizeof(float);           // 20,480,000
    const size_t NHb = (size_t)N_NODES * H * sizeof(unsigned short);  // 10,240,000
    float*          h     = (float*)(ws);
    unsigned short* xxbf  = (unsigned short*)(ws + NHf);
    unsigned short* x0bf  = (unsigned short*)(ws + NHf + NHb);
    unsigned short* hbf   = (unsigned short*)(ws + NHf + 2 * NHb);
    char* p = ws + NHf + 3 * NHb;
    unsigned short* Wtbf  = (unsigned short*)p;  p += 8 * H * H * 2;  // 262,144
    int*  counts  = (int*) p;  p += 160256;
    int*  row_ptr = (int*) p;  p += 160256;
    int*  cursor  = (int*) p;  p += 160256;
    int*  partial = (int*) p;  p += 1024;
    int2* ep      = (int2*)p;                    // NE * 8 bytes

    // CSR build (inputs restored pristine before every call)
    hipMemsetAsync(counts, 0, (size_t)N_NODES * 4, stream);
    k_hist   <<<NE / 256, 256, 0, stream>>>(erow, counts);
    k_scan1  <<<SCAN_B,   256, 0, stream>>>(counts, row_ptr, partial);
    k_scan2  <<<1,        256, 0, stream>>>(partial);
    k_scan3  <<<SCAN_B,   256, 0, stream>>>(partial, row_ptr, cursor);
    k_scatter<<<NE / 256, 256, 0, stream>>>(erow, ecol, ew, cursor, ep);

    // weight prep + input projection
    k_wprep<<<8 * H * H / 256, 256, 0, stream>>>(Wconv, Wtbf);
    k_xin  <<<N_NODES / 16,    256, 0, stream>>>(x, Win, bin, h, x0bf, hbf);

    // layers: spmm -> xxbf (bf16); gemm: h += relu(...), refresh hbf
    for (int l = 0; l < NLAYERS; l++) {
        float beta = logf(THETA / (float)(l + 1) + 1.0f);
        k_spmm<<<N_NODES / 4,  256, 0, stream>>>(row_ptr, ep, hbf, x0bf, xxbf);
        k_gemm<<<N_NODES / 64, 256, 0, stream>>>(xxbf, h, Wtbf + (size_t)l * H * H, hbf, beta);
    }

    // output projection
    k_out<<<N_NODES / 4, 256, 0, stream>>>(h, Wout, bout, out);
}